// Round 6
// baseline (469.480 us; speedup 1.0000x reference)
//
#include <hip/hip_runtime.h>
#include <math.h>

// StreamingKVCache — gather/shift/append + RoPE(keys, p<4096) over paged KV.
//   kv_cache: (2048 pages, 2, 16, 8, 128) f32 -> out same layout (268 MB)
//   k, v:     (4, 2048, 8, 128) f32
//   query_lens: int32[4]; B=4, 8192 positions/batch, H=8, D=128
// Memory-bound: ~537 MB traffic -> ~85 us @ 6.3 TB/s.
//
// Key structural facts exploited here:
//  - i = base + it*2^22: iteration stride only touches bits>=22, so
//    kv/slot/page-in-batch/h/d4/p are IDENTICAL across the 4 iterations.
//  - p, kv, srcp are wave-uniform (lanes only vary in bits<6 of i) ->
//    readfirstlane + SALU source selection, s_cselect'd base pointers.

typedef float f32x4 __attribute__((ext_vector_type(4)));

#define GRID_BLKS 16384
#define ITER_SPAN 4194304u     // 2^22 f4 = one batch's span
#define ROPE_P 4096
#define ROPE_J 64
#define LOG2_1E4_OVER_64 0.20762050593045951f  // log2(10000)/64

__global__ __launch_bounds__(256) void rope_table_k(float2* __restrict__ tab) {
    int i = blockIdx.x * 256 + threadIdx.x;
    if (i >= ROPE_P * ROPE_J) return;
    int p = i >> 6;
    int j = i & 63;
    float inv = exp2f(-LOG2_1E4_OVER_64 * (float)j);   // 10000^(-j/64)
    float s, c;
    sincosf((float)p * inv, &s, &c);
    tab[i] = make_float2(c, s);
}

__global__ __launch_bounds__(256) void kvcache_k(
    const f32x4* __restrict__ cache,   // f4 strides: page 8192, kv 4096, slot 256, h 32
    const f32x4* __restrict__ kin,     // f4 strides: b 524288, s 256, h 32
    const f32x4* __restrict__ vin,
    const int*   __restrict__ qls,
    const float2* __restrict__ rope,   // [4096][64] (cos,sin)
    f32x4*       __restrict__ out)
{
    const unsigned base    = blockIdx.x * 256u + threadIdx.x;
    const unsigned row0    = __builtin_amdgcn_readfirstlane(base >> 6);  // wave-uniform
    const unsigned lane_f4 = base & 63u;                                  // per-lane

    // Row-group decode (same for all 4 batches):
    const unsigned h_hi = row0 & 3u;             // h >> 1
    const unsigned slot = (row0 >> 2) & 15u;
    const unsigned kv   = (row0 >> 6) & 1u;
    const unsigned page = (row0 >> 7) & 511u;    // page within batch
    const unsigned p    = (page << 4) | slot;    // position in batch [0,8192)
    const unsigned d4   = base & 31u;

    // RoPE coefficients: p identical across iterations -> load once.
    const unsigned jb   = (d4 & 15u) * 4u;       // freq base [0,64)
    const unsigned prow = p < 4096u ? p : 0u;    // keep address valid when unused
    const f32x4* rp  = (const f32x4*)(rope + (size_t)prow * 64u + jb);
    const f32x4 cs01 = rp[0];                    // c0 s0 c1 s1
    const f32x4 cs23 = rp[1];                    // c2 s2 c3 s3
    const bool do_rope = (kv == 0u) && (p < 4096u);   // wave-uniform

    const int qlv[4] = { __builtin_amdgcn_readfirstlane(qls[0]),
                         __builtin_amdgcn_readfirstlane(qls[1]),
                         __builtin_amdgcn_readfirstlane(qls[2]),
                         __builtin_amdgcn_readfirstlane(qls[3]) };

    f32x4 x[4];
#pragma unroll
    for (int it = 0; it < 4; ++it) {
        const int  ql      = qlv[it];
        const bool rolling = ql > 1024;          // 3072 + ql > 4096
        const bool in_shift = rolling & ((int)p >= 4) & ((int)p < 4096 - ql);
        const bool in_app   = rolling ? (((int)p >= 4096 - ql) & (p < 4096u))
                                      : ((ql > 0) & (p >= 3072u) & ((int)p < 3072 + ql));
        int srcp = in_shift ? (int)p + ql - 1024                       // shift window
                 : in_app   ? (rolling ? (int)p - (4096 - ql)          // rolling append
                                       : (int)p - 3072)                // plain append
                 : (int)p;                                             // identity
        if (srcp < 0) srcp = 0;
        if (in_app) { if (srcp > 2047) srcp = 2047; }
        else        { if (srcp > 8191) srcp = 8191; }

        const unsigned g = (unsigned)it * 8192u + (unsigned)srcp;
        const size_t off_cache = (size_t)(g >> 4) * 8192u + (size_t)kv * 4096u
                               + (size_t)(g & 15u) * 256u;
        const size_t off_new   = (size_t)it * 524288u + (size_t)srcp * 256u;
        const f32x4* nb = kv ? vin : kin;
        const f32x4* sb = in_app ? (nb + off_new) : (cache + off_cache);  // s_cselect
        x[it] = __builtin_nontemporal_load(sb + (size_t)h_hi * 64u + lane_f4);
    }

    if (do_rope) {
        // r = x*c + sgn*y*s  (sgn=-1 lower half, +1 upper half) — branchless
        const float sgn = (d4 < 16u) ? -1.0f : 1.0f;
        const float s0 = cs01[1] * sgn, s1 = cs01[3] * sgn;
        const float s2 = cs23[1] * sgn, s3 = cs23[3] * sgn;
#pragma unroll
        for (int it = 0; it < 4; ++it) {
            f32x4 xx = x[it];
            f32x4 y;
            y[0] = __shfl_xor(xx[0], 16);
            y[1] = __shfl_xor(xx[1], 16);
            y[2] = __shfl_xor(xx[2], 16);
            y[3] = __shfl_xor(xx[3], 16);
            f32x4 r;
            r[0] = xx[0] * cs01[0] + y[0] * s0;
            r[1] = xx[1] * cs01[2] + y[1] * s1;
            r[2] = xx[2] * cs23[0] + y[2] * s2;
            r[3] = xx[3] * cs23[2] + y[3] * s3;
            x[it] = r;
        }
    }

#pragma unroll
    for (int it = 0; it < 4; ++it) {
        __builtin_nontemporal_store(x[it], &out[base + (unsigned)it * ITER_SPAN]);
    }
}

extern "C" void kernel_launch(void* const* d_in, const int* in_sizes, int n_in,
                              void* d_out, int out_size, void* d_ws, size_t ws_size,
                              hipStream_t stream) {
    const f32x4* cache = (const f32x4*)d_in[0];
    const f32x4* kin   = (const f32x4*)d_in[1];
    const f32x4* vin   = (const f32x4*)d_in[2];
    const int*   qls   = (const int*)d_in[3];
    f32x4*       out   = (f32x4*)d_out;

    float2* rope = (float2*)d_ws;   // 2 MB table in workspace
    rope_table_k<<<(ROPE_P * ROPE_J + 255) / 256, 256, 0, stream>>>(rope);

    kvcache_k<<<GRID_BLKS, 256, 0, stream>>>(cache, kin, vin, qls, rope, out);
}

// Round 7
// 463.535 us; speedup vs baseline: 1.0128x; 1.0128x over previous
//
#include <hip/hip_runtime.h>
#include <math.h>

// StreamingKVCache — gather/shift/append + RoPE(keys, p<4096) over paged KV.
//   kv_cache: (2048 pages, 2, 16, 8, 128) f32 -> out same layout (268 MB)
//   k, v:     (4, 2048, 8, 128) f32
//   query_lens: int32[4]; B=4, 8192 positions/batch, H=8, D=128
// Memory-bound: ~537 MB traffic -> ~85 us @ 6.3 TB/s achievable.
//
// Structure:
//  - One thread per 16B of output column, 4 batch-iterations per thread.
//    i = base + it*2^22: stride touches only bits>=22, so kv/slot/page/h/d4/p
//    are IDENTICAL across iterations -> decode once, RoPE coeffs once.
//  - p/kv/srcp wave-uniform (lanes vary only in bits<6) -> SALU selection,
//    s_cselect'd base pointers, 4 independent coalesced 1KB/wave loads.
//  - RoPE inline (sincosf), computed only on the 1/4 of waves that need it,
//    hidden under HBM load latency. No table, no second kernel, no d_ws use.

typedef float f32x4 __attribute__((ext_vector_type(4)));

#define GRID_BLKS 16384
#define ITER_SPAN 4194304u     // 2^22 f4 = one batch's span
#define LOG2_1E4_OVER_64 0.20762050593045951f  // log2(10000)/64

__global__ __launch_bounds__(256) void kvcache_k(
    const f32x4* __restrict__ cache,   // f4 strides: page 8192, kv 4096, slot 256, h 32
    const f32x4* __restrict__ kin,     // f4 strides: b 524288, s 256, h 32
    const f32x4* __restrict__ vin,
    const int*   __restrict__ qls,
    f32x4*       __restrict__ out)
{
    const unsigned base    = blockIdx.x * 256u + threadIdx.x;
    const unsigned row0    = __builtin_amdgcn_readfirstlane(base >> 6);  // wave-uniform
    const unsigned lane_f4 = base & 63u;                                  // per-lane

    // Row-group decode (same for all 4 batches):
    const unsigned h_hi = row0 & 3u;             // h >> 1
    const unsigned slot = (row0 >> 2) & 15u;
    const unsigned kv   = (row0 >> 6) & 1u;
    const unsigned page = (row0 >> 7) & 511u;    // page within batch
    const unsigned p    = (page << 4) | slot;    // position in batch [0,8192)
    const unsigned d4   = base & 31u;

    const int qlv[4] = { __builtin_amdgcn_readfirstlane(qls[0]),
                         __builtin_amdgcn_readfirstlane(qls[1]),
                         __builtin_amdgcn_readfirstlane(qls[2]),
                         __builtin_amdgcn_readfirstlane(qls[3]) };

    // Issue all 4 loads first — everything below hides under their latency.
    f32x4 x[4];
#pragma unroll
    for (int it = 0; it < 4; ++it) {
        const int  ql       = qlv[it];
        const bool rolling  = ql > 1024;         // 3072 + ql > 4096
        const bool in_shift = rolling & ((int)p >= 4) & ((int)p < 4096 - ql);
        const bool in_app   = rolling ? (((int)p >= 4096 - ql) & (p < 4096u))
                                      : ((ql > 0) & (p >= 3072u) & ((int)p < 3072 + ql));
        int srcp = in_shift ? (int)p + ql - 1024                       // shift window
                 : in_app   ? (rolling ? (int)p - (4096 - ql)          // rolling append
                                       : (int)p - 3072)                // plain append
                 : (int)p;                                             // identity
        if (srcp < 0) srcp = 0;
        if (in_app) { if (srcp > 2047) srcp = 2047; }
        else        { if (srcp > 8191) srcp = 8191; }

        const unsigned g = (unsigned)it * 8192u + (unsigned)srcp;
        const size_t off_cache = (size_t)(g >> 4) * 8192u + (size_t)kv * 4096u
                               + (size_t)(g & 15u) * 256u;
        const size_t off_new   = (size_t)it * 524288u + (size_t)srcp * 256u;
        const f32x4* nb = kv ? vin : kin;
        const f32x4* sb = in_app ? (nb + off_new) : (cache + off_cache);  // s_cselect
        x[it] = __builtin_nontemporal_load(sb + (size_t)h_hi * 64u + lane_f4);
    }

    // RoPE on keys at positions < 4096 (wave-uniform condition).
    const bool do_rope = (kv == 0u) && (p < 4096u);
    if (do_rope) {
        // Inline coefficients (shared by all 4 iterations); 4 sincosf per
        // thread on 1/4 of waves — fully hidden under the load latency.
        const unsigned jb = (d4 & 15u) * 4u;     // freq index base [0,64)
        float c[4], s[4];
#pragma unroll
        for (int q = 0; q < 4; ++q) {
            float inv = exp2f(-LOG2_1E4_OVER_64 * (float)(jb + (unsigned)q));
            sincosf((float)p * inv, &s[q], &c[q]);
        }
        // r = x*c + sgn*y*s  (sgn=-1 lower half, +1 upper half) — branchless
        const float sgn = (d4 < 16u) ? -1.0f : 1.0f;
        const float s0 = s[0] * sgn, s1 = s[1] * sgn;
        const float s2 = s[2] * sgn, s3 = s[3] * sgn;
#pragma unroll
        for (int it = 0; it < 4; ++it) {
            f32x4 xx = x[it];
            f32x4 y;
            y[0] = __shfl_xor(xx[0], 16);   // partner lane holds other head-half
            y[1] = __shfl_xor(xx[1], 16);
            y[2] = __shfl_xor(xx[2], 16);
            y[3] = __shfl_xor(xx[3], 16);
            f32x4 r;
            r[0] = xx[0] * c[0] + y[0] * s0;
            r[1] = xx[1] * c[1] + y[1] * s1;
            r[2] = xx[2] * c[2] + y[2] * s2;
            r[3] = xx[3] * c[3] + y[3] * s3;
            x[it] = r;
        }
    }

#pragma unroll
    for (int it = 0; it < 4; ++it) {
        __builtin_nontemporal_store(x[it], &out[base + (unsigned)it * ITER_SPAN]);
    }
}

extern "C" void kernel_launch(void* const* d_in, const int* in_sizes, int n_in,
                              void* d_out, int out_size, void* d_ws, size_t ws_size,
                              hipStream_t stream) {
    const f32x4* cache = (const f32x4*)d_in[0];
    const f32x4* kin   = (const f32x4*)d_in[1];
    const f32x4* vin   = (const f32x4*)d_in[2];
    const int*   qls   = (const int*)d_in[3];
    f32x4*       out   = (f32x4*)d_out;

    kvcache_k<<<GRID_BLKS, 256, 0, stream>>>(cache, kin, vin, qls, out);
}

// Round 8
// 460.873 us; speedup vs baseline: 1.0187x; 1.0058x over previous
//
#include <hip/hip_runtime.h>
#include <math.h>

// StreamingKVCache — gather/shift/append + RoPE(keys, p<4096) over paged KV.
//   kv_cache: (2048 pages, 2, 16, 8, 128) f32 -> out same layout (268 MB)
//   k, v:     (4, 2048, 8, 128) f32
//   query_lens: int32[4]; B=4, 8192 positions/batch, H=8, D=128
// Memory-bound: ~537 MB traffic -> ~85 us @ 6.3 TB/s achievable.
//
// Structure (r8): one thread owns BOTH kv=0 (key) and kv=1 (value) for the
// same (batch-iter, p, h, d4):
//   flat f4 index i = it(2b@22) | pagein(9b@13) | kv(1b@12) | slot(4b@8)
//                     | h(3b@5) | d4(5b@0)
//   thread id t     = pagein(9b@12) | slot(4b@8) | h(3b@5) | d4(5b@0)
// -> source selection (srcp/in_app) computed ONCE per batch for both kv;
//    8 independent 16B loads in flight; V-half stores independent of RoPE.
// p/slot/pagein wave-uniform (lanes vary in bits<6 only) -> SALU selection.

typedef float f32x4 __attribute__((ext_vector_type(4)));

#define GRID_BLKS 8192
#define LOG2_1E4_OVER_64 0.20762050593045951f  // log2(10000)/64

__global__ __launch_bounds__(256) void kvcache_k(
    const f32x4* __restrict__ cache,   // f4 strides: page 8192, kv 4096, slot 256, h 32
    const f32x4* __restrict__ kin,     // f4 strides: b 524288, s 256, h 32
    const f32x4* __restrict__ vin,
    const int*   __restrict__ qls,
    f32x4*       __restrict__ out)
{
    const unsigned t      = blockIdx.x * 256u + threadIdx.x;   // [0, 2^21)
    const unsigned low12  = t & 4095u;        // slot|h|d4  (i bits 0..11)
    const unsigned lowoff = t & 255u;         // h*32 + d4 (within 16-pos row)
    const unsigned d4     = t & 31u;
    const unsigned row0   = __builtin_amdgcn_readfirstlane(t >> 6);  // uniform
    const unsigned slot   = (row0 >> 2) & 15u;
    const unsigned pagein = row0 >> 6;        // page within batch [0,512)
    const unsigned p      = (pagein << 4) | slot;   // position [0,8192)

    const int qlv[4] = { __builtin_amdgcn_readfirstlane(qls[0]),
                         __builtin_amdgcn_readfirstlane(qls[1]),
                         __builtin_amdgcn_readfirstlane(qls[2]),
                         __builtin_amdgcn_readfirstlane(qls[3]) };

    // Issue all 8 loads up front; selection math shared across the kv pair.
    f32x4 xk[4], xv[4];
#pragma unroll
    for (int it = 0; it < 4; ++it) {
        const int  ql       = qlv[it];
        const bool rolling  = ql > 1024;       // 3072 + ql > 4096
        const bool in_shift = rolling & ((int)p >= 4) & ((int)p < 4096 - ql);
        const bool in_app   = rolling ? (((int)p >= 4096 - ql) & (p < 4096u))
                                      : ((ql > 0) & (p >= 3072u) & ((int)p < 3072 + ql));
        int srcp = in_shift ? (int)p + ql - 1024                      // shift window
                 : in_app   ? (rolling ? (int)p - (4096 - ql)         // rolling append
                                       : (int)p - 3072)               // plain append
                 : (int)p;                                            // identity
        if (srcp < 0) srcp = 0;
        if (in_app) { if (srcp > 2047) srcp = 2047; }
        else        { if (srcp > 8191) srcp = 8191; }

        const unsigned g = (unsigned)it * 8192u + (unsigned)srcp;
        const size_t offc = (size_t)(g >> 4) * 8192u + (size_t)(g & 15u) * 256u
                          + lowoff;                       // cache, kv=0
        const size_t offn = (size_t)it * 524288u + (size_t)srcp * 256u + lowoff;
        const f32x4* pk = in_app ? (kin + offn) : (cache + offc);          // s_cselect
        const f32x4* pv = in_app ? (vin + offn) : (cache + offc + 4096u);
        xk[it] = __builtin_nontemporal_load(pk);
        xv[it] = __builtin_nontemporal_load(pv);
    }

    // RoPE on the key half, positions < 4096 (wave-uniform condition).
    if (p < 4096u) {
        const unsigned jb = (d4 & 15u) * 4u;   // freq index base [0,64)
        float c[4], s[4];
#pragma unroll
        for (int q = 0; q < 4; ++q) {
            float inv = exp2f(-LOG2_1E4_OVER_64 * (float)(jb + (unsigned)q));
            sincosf((float)p * inv, &s[q], &c[q]);
        }
        // r = x*c + sgn*y*s  (sgn=-1 lower half, +1 upper half) — branchless
        const float sgn = (d4 < 16u) ? -1.0f : 1.0f;
        const float s0 = s[0] * sgn, s1 = s[1] * sgn;
        const float s2 = s[2] * sgn, s3 = s[3] * sgn;
#pragma unroll
        for (int it = 0; it < 4; ++it) {
            f32x4 xx = xk[it];
            f32x4 y;
            y[0] = __shfl_xor(xx[0], 16);   // partner lane = other head-half
            y[1] = __shfl_xor(xx[1], 16);
            y[2] = __shfl_xor(xx[2], 16);
            y[3] = __shfl_xor(xx[3], 16);
            f32x4 r;
            r[0] = xx[0] * c[0] + y[0] * s0;
            r[1] = xx[1] * c[1] + y[1] * s1;
            r[2] = xx[2] * c[2] + y[2] * s2;
            r[3] = xx[3] * c[3] + y[3] * s3;
            xk[it] = r;
        }
    }

#pragma unroll
    for (int it = 0; it < 4; ++it) {
        const size_t o0 = ((size_t)it << 22) | ((size_t)pagein << 13) | low12;
        __builtin_nontemporal_store(xk[it], &out[o0]);            // kv=0
        __builtin_nontemporal_store(xv[it], &out[o0 + 4096u]);    // kv=1
    }
}

extern "C" void kernel_launch(void* const* d_in, const int* in_sizes, int n_in,
                              void* d_out, int out_size, void* d_ws, size_t ws_size,
                              hipStream_t stream) {
    const f32x4* cache = (const f32x4*)d_in[0];
    const f32x4* kin   = (const f32x4*)d_in[1];
    const f32x4* vin   = (const f32x4*)d_in[2];
    const int*   qls   = (const int*)d_in[3];
    f32x4*       out   = (f32x4*)d_out;

    kvcache_k<<<GRID_BLKS, 256, 0, stream>>>(cache, kin, vin, qls, out);
}